// Round 1
// baseline (759.335 us; speedup 1.0000x reference)
//
#include <hip/hip_runtime.h>
#include <cstdint>

#define NN 100000
#define NE 640000
#define DIN 128
#define DOUT 256
#define LN_EPS 1e-5f

// ---- workspace layout (bytes) ----
// [0,       131072)  Wlt  : W_l transposed  [DIN][DOUT] f32
// [131072,  262144)  Wrt  : W_r transposed
// [262144,  393216)  Wpt  : W_proj transposed
// [393216,  +N*DIN*4) summed : [NN][DIN] f32   (zeroed each call)
// then               cnt    : [NN] f32         (zeroed each call)
#define WS_WLT 0
#define WS_WRT 131072
#define WS_WPT 262144
#define WS_SUM 393216
#define WS_CNT (WS_SUM + (size_t)NN * DIN * 4)
#define WS_ZERO_BYTES ((size_t)NN * DIN * 4 + (size_t)NN * 4)

__global__ void transpose_w_kernel(const float* __restrict__ W, float* __restrict__ Wt) {
    int idx = blockIdx.x * blockDim.x + threadIdx.x;   // idx = k*DOUT + c
    if (idx >= DIN * DOUT) return;
    int k = idx >> 8;
    int c = idx & (DOUT - 1);
    Wt[idx] = W[c * DIN + k];
}

// one (edge, feat) pair per thread; 128 consecutive threads share one edge
__global__ __launch_bounds__(256)
void aggregate_kernel(const float* __restrict__ x, const int* __restrict__ ei,
                      float* __restrict__ summed, float* __restrict__ cnt) {
    long long idx = (long long)blockIdx.x * blockDim.x + threadIdx.x;
    const long long total = (long long)NE * DIN;
    if (idx >= total) return;
    int e = (int)(idx >> 7);
    int f = (int)(idx & (DIN - 1));
    int src = ei[e];
    int dst = ei[NE + e];
    atomicAdd(&summed[(long long)dst * DIN + f], x[(long long)src * DIN + f]);
    if (f == 0) atomicAdd(&cnt[dst], 1.0f);
}

// 8 nodes per block, 256 threads; thread c owns output channel c for all 8 nodes
__global__ __launch_bounds__(256)
void fused_node_kernel(const float* __restrict__ x, const float* __restrict__ summed,
                       const float* __restrict__ cnt,
                       const float* __restrict__ Wlt, const float* __restrict__ Wrt,
                       const float* __restrict__ Wpt,
                       const float* __restrict__ b_l, const float* __restrict__ gamma,
                       const float* __restrict__ beta, float* __restrict__ out) {
    __shared__ float xs[8][DIN];
    __shared__ float as[8][DIN];
    __shared__ float inv[8];
    __shared__ float red[8];

    const int t = threadIdx.x;
    const int base = blockIdx.x * 8;   // NN == 12500*8, no boundary

    if (t < 8) inv[t] = 1.0f / fmaxf(cnt[base + t], 1.0f);
    __syncthreads();

    for (int i = t; i < 8 * DIN; i += 256) {
        int j = i >> 7, f = i & (DIN - 1);
        xs[j][f] = x[(long long)(base + j) * DIN + f];
        as[j][f] = summed[(long long)(base + j) * DIN + f] * inv[j];
    }
    __syncthreads();

    const int c = t;
    float h[8], p[8];
#pragma unroll
    for (int j = 0; j < 8; ++j) { h[j] = 0.0f; p[j] = 0.0f; }

    for (int k = 0; k < DIN; ++k) {
        float wl = Wlt[k * DOUT + c];
        float wr = Wrt[k * DOUT + c];
        float wp = Wpt[k * DOUT + c];
#pragma unroll
        for (int j = 0; j < 8; ++j) {
            h[j] = fmaf(as[j][k], wl, h[j]);
            h[j] = fmaf(xs[j][k], wr, h[j]);
            p[j] = fmaf(xs[j][k], wp, p[j]);
        }
    }

    const float bl = b_l[c], gm = gamma[c], bt = beta[c];
    const int wid = t >> 6, lane = t & 63;

    for (int j = 0; j < 8; ++j) {
        float v = h[j] + bl;
        float s = v, s2 = v * v;
#pragma unroll
        for (int o = 32; o > 0; o >>= 1) {
            s += __shfl_xor(s, o);
            s2 += __shfl_xor(s2, o);
        }
        if (lane == 0) { red[wid] = s; red[4 + wid] = s2; }
        __syncthreads();
        float mu = (red[0] + red[1] + red[2] + red[3]) * (1.0f / DOUT);
        float m2 = (red[4] + red[5] + red[6] + red[7]) * (1.0f / DOUT);
        float var = m2 - mu * mu;
        float nrm = (v - mu) * rsqrtf(var + LN_EPS) * gm + bt;
        float g = 0.5f * nrm * (1.0f + erff(nrm * 0.70710678118f));
        out[(long long)(base + j) * DOUT + c] = g + p[j];
        __syncthreads();   // red[] reused next j
    }
}

extern "C" void kernel_launch(void* const* d_in, const int* in_sizes, int n_in,
                              void* d_out, int out_size, void* d_ws, size_t ws_size,
                              hipStream_t stream) {
    const float* x      = (const float*)d_in[0];
    const int*   ei     = (const int*)d_in[1];
    const float* W_l    = (const float*)d_in[2];
    const float* b_l    = (const float*)d_in[3];
    const float* W_r    = (const float*)d_in[4];
    const float* gamma  = (const float*)d_in[5];
    const float* beta   = (const float*)d_in[6];
    const float* W_proj = (const float*)d_in[7];
    float* out = (float*)d_out;

    char* ws = (char*)d_ws;
    float* Wlt    = (float*)(ws + WS_WLT);
    float* Wrt    = (float*)(ws + WS_WRT);
    float* Wpt    = (float*)(ws + WS_WPT);
    float* summed = (float*)(ws + WS_SUM);
    float* cnt    = (float*)(ws + WS_CNT);

    // zero the accumulation buffers (required every call)
    hipMemsetAsync(ws + WS_SUM, 0, WS_ZERO_BYTES, stream);

    // transpose weights to [DIN][DOUT]
    {
        dim3 g((DIN * DOUT + 255) / 256), b(256);
        transpose_w_kernel<<<g, b, 0, stream>>>(W_l, Wlt);
        transpose_w_kernel<<<g, b, 0, stream>>>(W_r, Wrt);
        transpose_w_kernel<<<g, b, 0, stream>>>(W_proj, Wpt);
    }

    // edge aggregation (atomics)
    {
        long long total = (long long)NE * DIN;
        int blocks = (int)((total + 255) / 256);
        aggregate_kernel<<<blocks, 256, 0, stream>>>(x, ei, summed, cnt);
    }

    // fused SAGE + LN + GELU + residual
    {
        fused_node_kernel<<<NN / 8, 256, 0, stream>>>(
            x, summed, cnt, Wlt, Wrt, Wpt, b_l, gamma, beta, out);
    }
}

// Round 2
// 417.274 us; speedup vs baseline: 1.8198x; 1.8198x over previous
//
#include <hip/hip_runtime.h>
#include <cstdint>

#define NN 100000
#define NE 640000
#define DIN 128
#define DOUT 256
#define LN_EPS 1e-5f

typedef __attribute__((ext_vector_type(8))) short bf16x8;
typedef __attribute__((ext_vector_type(4))) float f32x4;

// ---- workspace layout (bytes) ----
// [0, 65536)        pkWl : W_l packed bf16 MFMA-B fragments
// [65536, 131072)   pkWr
// [131072, 196608)  pkWp
// [196608, +N*DIN*4) summed (zeroed each call)
// then              cnt [NN] f32 (zeroed each call)
#define WS_PKL 0
#define WS_PKR 65536
#define WS_PKP 131072
#define WS_SUM 196608
#define WS_CNT (WS_SUM + (size_t)NN * DIN * 4)
#define WS_ZERO_BYTES ((size_t)NN * DIN * 4 + (size_t)NN * 4)

static __device__ __forceinline__ unsigned short f2bf(float f) {
    unsigned u = __builtin_bit_cast(unsigned, f);
    u += 0x7FFFu + ((u >> 16) & 1u);          // round-to-nearest-even
    return (unsigned short)(u >> 16);
}

// Pack W [DOUT][DIN] f32 -> bf16 B-fragment layout for mfma_f32_16x16x32_bf16.
// Fragment (kt in 0..3, ct in 0..15): lane l holds col n = ct*16+(l&15),
// k = kt*32 + (l>>4)*8 + i (i=0..7 contiguous). Linear: ((kt*16+ct)*64+l)*8+i.
__global__ __launch_bounds__(256)
void pack_w_kernel(const float* __restrict__ W, unsigned short* __restrict__ pk) {
    int t2 = blockIdx.x * 256 + threadIdx.x;
    if (t2 >= 4096) return;
    int kt = t2 >> 10;
    int ct = (t2 >> 6) & 15;
    int l  = t2 & 63;
    int n  = ct * 16 + (l & 15);
    int kb = kt * 32 + (l >> 4) * 8;
    const float4* wp = (const float4*)(W + n * DIN + kb);
    float4 a = wp[0], b = wp[1];
    unsigned short v[8];
    v[0]=f2bf(a.x); v[1]=f2bf(a.y); v[2]=f2bf(a.z); v[3]=f2bf(a.w);
    v[4]=f2bf(b.x); v[5]=f2bf(b.y); v[6]=f2bf(b.z); v[7]=f2bf(b.w);
    bf16x8 o;
#pragma unroll
    for (int i = 0; i < 8; ++i) o[i] = (short)v[i];
    *(bf16x8*)(pk + (size_t)t2 * 8) = o;
}

// one (edge, feat) pair per thread; 128 consecutive threads share one edge
__global__ __launch_bounds__(256)
void aggregate_kernel(const float* __restrict__ x, const int* __restrict__ ei,
                      float* __restrict__ summed, float* __restrict__ cnt) {
    long long idx = (long long)blockIdx.x * blockDim.x + threadIdx.x;
    const long long total = (long long)NE * DIN;
    if (idx >= total) return;
    int e = (int)(idx >> 7);
    int f = (int)(idx & (DIN - 1));
    int src = ei[e];
    int dst = ei[NE + e];
    atomicAdd(&summed[(long long)dst * DIN + f], x[(long long)src * DIN + f]);
    if (f == 0) atomicAdd(&cnt[dst], 1.0f);
}

// 64 nodes/block, 256 threads = 4 waves. Wave w owns output cols [w*64, w*64+64).
// Three GEMMs via mfma_f32_16x16x32_bf16, LN in-register, GELU, residual.
__global__ __launch_bounds__(256, 2)
void fused_mfma_kernel(const float* __restrict__ x, const float* __restrict__ summed,
                       const float* __restrict__ cnt,
                       const unsigned short* __restrict__ pkWl,
                       const unsigned short* __restrict__ pkWr,
                       const unsigned short* __restrict__ pkWp,
                       const float* __restrict__ b_l, const float* __restrict__ gamma,
                       const float* __restrict__ beta, float* __restrict__ out) {
    __shared__ unsigned short xsPk[4 * 4 * 64 * 8];   // [rt][kt][l][8] bf16, 16 KB
    __shared__ unsigned short agPk[4 * 4 * 64 * 8];
    __shared__ float invS[64];
    __shared__ float redS[4][64], redS2[4][64];
    __shared__ float muS[64], rsS[64];

    const int t = threadIdx.x;
    const int base = blockIdx.x * 64;

    if (t < 64) {
        int r = base + t;
        invS[t] = (r < NN) ? 1.0f / fmaxf(cnt[r], 1.0f) : 0.0f;
    }
    __syncthreads();

    // stage x and agg=summed*inv into A-fragment layout (bf16)
    for (int task = t; task < 1024; task += 256) {
        int l  = task & 63;
        int kt = (task >> 6) & 3;
        int rt = task >> 8;
        int row = rt * 16 + (l & 15);
        int r = base + row;
        int kb = kt * 32 + (l >> 4) * 8;
        bf16x8 vx = {}, vg = {};
        if (r < NN) {
            const float4* xp = (const float4*)(x + (size_t)r * DIN + kb);
            const float4* gp = (const float4*)(summed + (size_t)r * DIN + kb);
            float4 x0 = xp[0], x1 = xp[1];
            float4 g0 = gp[0], g1 = gp[1];
            float iv = invS[row];
            vx[0]=(short)f2bf(x0.x); vx[1]=(short)f2bf(x0.y); vx[2]=(short)f2bf(x0.z); vx[3]=(short)f2bf(x0.w);
            vx[4]=(short)f2bf(x1.x); vx[5]=(short)f2bf(x1.y); vx[6]=(short)f2bf(x1.z); vx[7]=(short)f2bf(x1.w);
            vg[0]=(short)f2bf(g0.x*iv); vg[1]=(short)f2bf(g0.y*iv); vg[2]=(short)f2bf(g0.z*iv); vg[3]=(short)f2bf(g0.w*iv);
            vg[4]=(short)f2bf(g1.x*iv); vg[5]=(short)f2bf(g1.y*iv); vg[6]=(short)f2bf(g1.z*iv); vg[7]=(short)f2bf(g1.w*iv);
        }
        *(bf16x8*)&xsPk[(size_t)task * 8] = vx;
        *(bf16x8*)&agPk[(size_t)task * 8] = vg;
    }
    __syncthreads();

    const int w = t >> 6, l = t & 63;
    f32x4 h[4][4], p[4][4];
#pragma unroll
    for (int a = 0; a < 4; ++a)
#pragma unroll
        for (int b = 0; b < 4; ++b) { h[a][b] = (f32x4)(0.0f); p[a][b] = (f32x4)(0.0f); }

#pragma unroll
    for (int kt = 0; kt < 4; ++kt) {
        bf16x8 ax[4], ag[4];
#pragma unroll
        for (int rt = 0; rt < 4; ++rt) {
            size_t off = ((size_t)(rt * 4 + kt) * 64 + l) * 8;
            ax[rt] = *(const bf16x8*)&xsPk[off];
            ag[rt] = *(const bf16x8*)&agPk[off];
        }
#pragma unroll
        for (int ct = 0; ct < 4; ++ct) {
            int gct = w * 4 + ct;
            size_t boff = ((size_t)(kt * 16 + gct) * 64 + l) * 8;
            bf16x8 bl = *(const bf16x8*)(pkWl + boff);
            bf16x8 br = *(const bf16x8*)(pkWr + boff);
            bf16x8 bp = *(const bf16x8*)(pkWp + boff);
#pragma unroll
            for (int rt = 0; rt < 4; ++rt) {
                h[rt][ct] = __builtin_amdgcn_mfma_f32_16x16x32_bf16(ag[rt], bl, h[rt][ct], 0, 0, 0);
                h[rt][ct] = __builtin_amdgcn_mfma_f32_16x16x32_bf16(ax[rt], br, h[rt][ct], 0, 0, 0);
                p[rt][ct] = __builtin_amdgcn_mfma_f32_16x16x32_bf16(ax[rt], bp, p[rt][ct], 0, 0, 0);
            }
        }
    }

    // per-lane column params (col = w*64 + ct*16 + (l&15))
    float bl4[4], gm4[4], bt4[4];
#pragma unroll
    for (int ct = 0; ct < 4; ++ct) {
        int n = w * 64 + ct * 16 + (l & 15);
        bl4[ct] = b_l[n]; gm4[ct] = gamma[n]; bt4[ct] = beta[n];
    }

    // add bias; per-row partial sums over this wave's 64 cols
#pragma unroll
    for (int rt = 0; rt < 4; ++rt) {
        float s[4] = {0, 0, 0, 0}, s2[4] = {0, 0, 0, 0};
#pragma unroll
        for (int ct = 0; ct < 4; ++ct)
#pragma unroll
            for (int j = 0; j < 4; ++j) {
                float v = h[rt][ct][j] + bl4[ct];
                h[rt][ct][j] = v;
                s[j] += v; s2[j] += v * v;
            }
        // reduce across the 16 lanes (l&15) holding the same rows
#pragma unroll
        for (int o = 1; o < 16; o <<= 1) {
#pragma unroll
            for (int j = 0; j < 4; ++j) {
                s[j]  += __shfl_xor(s[j], o);
                s2[j] += __shfl_xor(s2[j], o);
            }
        }
        if ((l & 15) == 0) {
#pragma unroll
            for (int j = 0; j < 4; ++j) {
                int row = rt * 16 + (l >> 4) * 4 + j;
                redS[w][row] = s[j]; redS2[w][row] = s2[j];
            }
        }
    }
    __syncthreads();

    if (t < 64) {
        float mu = (redS[0][t] + redS[1][t] + redS[2][t] + redS[3][t]) * (1.0f / DOUT);
        float m2 = (redS2[0][t] + redS2[1][t] + redS2[2][t] + redS2[3][t]) * (1.0f / DOUT);
        float var = m2 - mu * mu;
        muS[t] = mu;
        rsS[t] = rsqrtf(var + LN_EPS);
    }
    __syncthreads();

    // LN + GELU + residual, store
#pragma unroll
    for (int rt = 0; rt < 4; ++rt) {
#pragma unroll
        for (int j = 0; j < 4; ++j) {
            int m = (l >> 4) * 4 + j;
            int row = rt * 16 + m;
            int r = base + row;
            if (r >= NN) continue;
            float mu = muS[row], rs = rsS[row];
#pragma unroll
            for (int ct = 0; ct < 4; ++ct) {
                float v = h[rt][ct][j];
                float nrm = (v - mu) * rs * gm4[ct] + bt4[ct];
                float g = 0.5f * nrm * (1.0f + erff(nrm * 0.70710678118f));
                int n = w * 64 + ct * 16 + (l & 15);
                out[(size_t)r * DOUT + n] = g + p[rt][ct][j];
            }
        }
    }
}

extern "C" void kernel_launch(void* const* d_in, const int* in_sizes, int n_in,
                              void* d_out, int out_size, void* d_ws, size_t ws_size,
                              hipStream_t stream) {
    const float* x      = (const float*)d_in[0];
    const int*   ei     = (const int*)d_in[1];
    const float* W_l    = (const float*)d_in[2];
    const float* b_l    = (const float*)d_in[3];
    const float* W_r    = (const float*)d_in[4];
    const float* gamma  = (const float*)d_in[5];
    const float* beta   = (const float*)d_in[6];
    const float* W_proj = (const float*)d_in[7];
    float* out = (float*)d_out;

    char* ws = (char*)d_ws;
    unsigned short* pkWl = (unsigned short*)(ws + WS_PKL);
    unsigned short* pkWr = (unsigned short*)(ws + WS_PKR);
    unsigned short* pkWp = (unsigned short*)(ws + WS_PKP);
    float* summed = (float*)(ws + WS_SUM);
    float* cnt    = (float*)(ws + WS_CNT);

    hipMemsetAsync(ws + WS_SUM, 0, WS_ZERO_BYTES, stream);

    pack_w_kernel<<<16, 256, 0, stream>>>(W_l, pkWl);
    pack_w_kernel<<<16, 256, 0, stream>>>(W_r, pkWr);
    pack_w_kernel<<<16, 256, 0, stream>>>(W_proj, pkWp);

    {
        long long total = (long long)NE * DIN;
        int blocks = (int)((total + 255) / 256);
        aggregate_kernel<<<blocks, 256, 0, stream>>>(x, ei, summed, cnt);
    }

    fused_mfma_kernel<<<(NN + 63) / 64, 256, 0, stream>>>(
        x, summed, cnt, pkWl, pkWr, pkWp, b_l, gamma, beta, out);
}

// Round 3
// 253.894 us; speedup vs baseline: 2.9908x; 1.6435x over previous
//
#include <hip/hip_runtime.h>
#include <cstdint>

#define NN 100000
#define NE 640000
#define DIN 128
#define DOUT 256
#define LN_EPS 1e-5f
#define NBLK_SCAN 391   // ceil(NN/256)

typedef __attribute__((ext_vector_type(8))) short bf16x8;
typedef __attribute__((ext_vector_type(4))) float f32x4;

// ---- workspace layout (bytes) ----
#define WS_PKL  0u
#define WS_PKR  65536u
#define WS_PKP  131072u
#define WS_AGG  196608u                          // [NN][DIN] f32 = 51,200,000
#define WS_CNTI (WS_AGG + (size_t)NN * DIN * 4)  // [NN] int (memset 0 each call)
#define WS_OFFS (WS_CNTI + (size_t)NN * 4)       // [NN+1] int
#define WS_CURS (WS_OFFS + (size_t)(NN + 1) * 4)
#define WS_BS1  (WS_CURS + (size_t)NN * 4)       // blockSums [NBLK_SCAN]
#define WS_BS2  (WS_BS1 + (size_t)NBLK_SCAN * 4) // scanned blockSums
#define WS_SRCI (WS_BS2 + (size_t)NBLK_SCAN * 4) // [NE] int

static __device__ __forceinline__ unsigned short f2bf(float f) {
    unsigned u = __builtin_bit_cast(unsigned, f);
    u += 0x7FFFu + ((u >> 16) & 1u);          // round-to-nearest-even
    return (unsigned short)(u >> 16);
}

// Pack W [DOUT][DIN] f32 -> bf16 B-fragment layout for mfma_f32_16x16x32_bf16.
__global__ __launch_bounds__(256)
void pack_w_kernel(const float* __restrict__ W, unsigned short* __restrict__ pk) {
    int t2 = blockIdx.x * 256 + threadIdx.x;
    if (t2 >= 4096) return;
    int kt = t2 >> 10;
    int ct = (t2 >> 6) & 15;
    int l  = t2 & 63;
    int n  = ct * 16 + (l & 15);
    int kb = kt * 32 + (l >> 4) * 8;
    const float4* wp = (const float4*)(W + n * DIN + kb);
    float4 a = wp[0], b = wp[1];
    bf16x8 o;
    o[0]=(short)f2bf(a.x); o[1]=(short)f2bf(a.y); o[2]=(short)f2bf(a.z); o[3]=(short)f2bf(a.w);
    o[4]=(short)f2bf(b.x); o[5]=(short)f2bf(b.y); o[6]=(short)f2bf(b.z); o[7]=(short)f2bf(b.w);
    *(bf16x8*)(pk + (size_t)t2 * 8) = o;
}

// ---- CSR build ----
__global__ __launch_bounds__(256)
void count_kernel(const int* __restrict__ ei, int* __restrict__ cnt) {
    int e = blockIdx.x * 256 + threadIdx.x;
    if (e >= NE) return;
    atomicAdd(&cnt[ei[NE + e]], 1);
}

__global__ __launch_bounds__(256)
void scan_block_sums(const int* __restrict__ cnt, int* __restrict__ blockSums) {
    __shared__ int red[256];
    int i = blockIdx.x * 256 + threadIdx.x;
    red[threadIdx.x] = (i < NN) ? cnt[i] : 0;
    __syncthreads();
    for (int o = 128; o > 0; o >>= 1) {
        if (threadIdx.x < o) red[threadIdx.x] += red[threadIdx.x + o];
        __syncthreads();
    }
    if (threadIdx.x == 0) blockSums[blockIdx.x] = red[0];
}

__global__ __launch_bounds__(512)
void scan_partials(const int* __restrict__ blockSums, int* __restrict__ bsumScan) {
    __shared__ int s[512];
    int t = threadIdx.x;
    int v = (t < NBLK_SCAN) ? blockSums[t] : 0;
    s[t] = v; __syncthreads();
    for (int o = 1; o < 512; o <<= 1) {
        int add = (t >= o) ? s[t - o] : 0;
        __syncthreads();
        s[t] += add;
        __syncthreads();
    }
    if (t < NBLK_SCAN) bsumScan[t] = s[t] - v;   // exclusive
}

__global__ __launch_bounds__(256)
void scan_final(const int* __restrict__ cnt, const int* __restrict__ bsumScan,
                int* __restrict__ offsets, int* __restrict__ cursor) {
    __shared__ int s[256];
    int t = threadIdx.x;
    int i = blockIdx.x * 256 + t;
    int v = (i < NN) ? cnt[i] : 0;
    s[t] = v; __syncthreads();
    for (int o = 1; o < 256; o <<= 1) {
        int add = (t >= o) ? s[t - o] : 0;
        __syncthreads();
        s[t] += add;
        __syncthreads();
    }
    int excl = s[t] - v + bsumScan[blockIdx.x];
    if (i < NN) {
        offsets[i] = excl;
        cursor[i]  = excl;
        if (i == NN - 1) offsets[NN] = excl + v;
    }
}

__global__ __launch_bounds__(256)
void scatter_kernel(const int* __restrict__ ei, int* __restrict__ cursor,
                    int* __restrict__ srcIdx) {
    int e = blockIdx.x * 256 + threadIdx.x;
    if (e >= NE) return;
    int src = ei[e], dst = ei[NE + e];
    int pos = atomicAdd(&cursor[dst], 1);
    srcIdx[pos] = src;
}

// one wave per node: gather neighbor rows, mean, write agg (scaled)
__global__ __launch_bounds__(256)
void csr_aggregate(const float* __restrict__ x, const int* __restrict__ srcIdx,
                   const int* __restrict__ offsets, float* __restrict__ agg) {
    int w = threadIdx.x >> 6, l = threadIdx.x & 63;
    int node = blockIdx.x * 4 + w;
    if (node >= NN) return;
    int beg = offsets[node], end = offsets[node + 1];
    float sx = 0.0f, sy = 0.0f;
    const float2* xb = (const float2*)x;
    for (int j = beg; j < end; ++j) {
        int s = srcIdx[j];
        float2 v = xb[(size_t)s * 64 + l];
        sx += v.x; sy += v.y;
    }
    float iv = 1.0f / fmaxf((float)(end - beg), 1.0f);
    float2 o; o.x = sx * iv; o.y = sy * iv;
    ((float2*)agg)[(size_t)node * 64 + l] = o;
}

// 64 nodes/block, 256 threads = 4 waves. Wave w owns output cols [w*64, w*64+64).
__global__ __launch_bounds__(256, 2)
void fused_mfma_kernel(const float* __restrict__ x, const float* __restrict__ agg,
                       const unsigned short* __restrict__ pkWl,
                       const unsigned short* __restrict__ pkWr,
                       const unsigned short* __restrict__ pkWp,
                       const float* __restrict__ b_l, const float* __restrict__ gamma,
                       const float* __restrict__ beta, float* __restrict__ out) {
    __shared__ unsigned short xsPk[4 * 4 * 64 * 8];   // [rt][kt][l][8] bf16, 16 KB
    __shared__ unsigned short agPk[4 * 4 * 64 * 8];
    __shared__ float redS[4][64], redS2[4][64];
    __shared__ float muS[64], rsS[64];

    const int t = threadIdx.x;
    const int base = blockIdx.x * 64;

    for (int task = t; task < 1024; task += 256) {
        int l  = task & 63;
        int kt = (task >> 6) & 3;
        int rt = task >> 8;
        int row = rt * 16 + (l & 15);
        int r = base + row;
        int kb = kt * 32 + (l >> 4) * 8;
        bf16x8 vx = {}, vg = {};
        if (r < NN) {
            const float4* xp = (const float4*)(x + (size_t)r * DIN + kb);
            const float4* gp = (const float4*)(agg + (size_t)r * DIN + kb);
            float4 x0 = xp[0], x1 = xp[1];
            float4 g0 = gp[0], g1 = gp[1];
            vx[0]=(short)f2bf(x0.x); vx[1]=(short)f2bf(x0.y); vx[2]=(short)f2bf(x0.z); vx[3]=(short)f2bf(x0.w);
            vx[4]=(short)f2bf(x1.x); vx[5]=(short)f2bf(x1.y); vx[6]=(short)f2bf(x1.z); vx[7]=(short)f2bf(x1.w);
            vg[0]=(short)f2bf(g0.x); vg[1]=(short)f2bf(g0.y); vg[2]=(short)f2bf(g0.z); vg[3]=(short)f2bf(g0.w);
            vg[4]=(short)f2bf(g1.x); vg[5]=(short)f2bf(g1.y); vg[6]=(short)f2bf(g1.z); vg[7]=(short)f2bf(g1.w);
        }
        *(bf16x8*)&xsPk[(size_t)task * 8] = vx;
        *(bf16x8*)&agPk[(size_t)task * 8] = vg;
    }
    __syncthreads();

    const int w = t >> 6, l = t & 63;
    f32x4 h[4][4], p[4][4];
#pragma unroll
    for (int a = 0; a < 4; ++a)
#pragma unroll
        for (int b = 0; b < 4; ++b) { h[a][b] = (f32x4)(0.0f); p[a][b] = (f32x4)(0.0f); }

#pragma unroll
    for (int kt = 0; kt < 4; ++kt) {
        bf16x8 ax[4], ag[4];
#pragma unroll
        for (int rt = 0; rt < 4; ++rt) {
            size_t off = ((size_t)(rt * 4 + kt) * 64 + l) * 8;
            ax[rt] = *(const bf16x8*)&xsPk[off];
            ag[rt] = *(const bf16x8*)&agPk[off];
        }
#pragma unroll
        for (int ct = 0; ct < 4; ++ct) {
            int gct = w * 4 + ct;
            size_t boff = ((size_t)(kt * 16 + gct) * 64 + l) * 8;
            bf16x8 bl = *(const bf16x8*)(pkWl + boff);
            bf16x8 br = *(const bf16x8*)(pkWr + boff);
            bf16x8 bp = *(const bf16x8*)(pkWp + boff);
#pragma unroll
            for (int rt = 0; rt < 4; ++rt) {
                h[rt][ct] = __builtin_amdgcn_mfma_f32_16x16x32_bf16(ag[rt], bl, h[rt][ct], 0, 0, 0);
                h[rt][ct] = __builtin_amdgcn_mfma_f32_16x16x32_bf16(ax[rt], br, h[rt][ct], 0, 0, 0);
                p[rt][ct] = __builtin_amdgcn_mfma_f32_16x16x32_bf16(ax[rt], bp, p[rt][ct], 0, 0, 0);
            }
        }
    }

    float bl4[4], gm4[4], bt4[4];
#pragma unroll
    for (int ct = 0; ct < 4; ++ct) {
        int n = w * 64 + ct * 16 + (l & 15);
        bl4[ct] = b_l[n]; gm4[ct] = gamma[n]; bt4[ct] = beta[n];
    }

#pragma unroll
    for (int rt = 0; rt < 4; ++rt) {
        float s[4] = {0, 0, 0, 0}, s2[4] = {0, 0, 0, 0};
#pragma unroll
        for (int ct = 0; ct < 4; ++ct)
#pragma unroll
            for (int j = 0; j < 4; ++j) {
                float v = h[rt][ct][j] + bl4[ct];
                h[rt][ct][j] = v;
                s[j] += v; s2[j] += v * v;
            }
#pragma unroll
        for (int o = 1; o < 16; o <<= 1) {
#pragma unroll
            for (int j = 0; j < 4; ++j) {
                s[j]  += __shfl_xor(s[j], o);
                s2[j] += __shfl_xor(s2[j], o);
            }
        }
        if ((l & 15) == 0) {
#pragma unroll
            for (int j = 0; j < 4; ++j) {
                int row = rt * 16 + (l >> 4) * 4 + j;
                redS[w][row] = s[j]; redS2[w][row] = s2[j];
            }
        }
    }
    __syncthreads();

    if (t < 64) {
        float mu = (redS[0][t] + redS[1][t] + redS[2][t] + redS[3][t]) * (1.0f / DOUT);
        float m2 = (redS2[0][t] + redS2[1][t] + redS2[2][t] + redS2[3][t]) * (1.0f / DOUT);
        float var = m2 - mu * mu;
        muS[t] = mu;
        rsS[t] = rsqrtf(var + LN_EPS);
    }
    __syncthreads();

#pragma unroll
    for (int rt = 0; rt < 4; ++rt) {
#pragma unroll
        for (int j = 0; j < 4; ++j) {
            int m = (l >> 4) * 4 + j;
            int row = rt * 16 + m;
            int r = base + row;
            if (r >= NN) continue;
            float mu = muS[row], rs = rsS[row];
#pragma unroll
            for (int ct = 0; ct < 4; ++ct) {
                float v = h[rt][ct][j];
                float nrm = (v - mu) * rs * gm4[ct] + bt4[ct];
                float g = 0.5f * nrm * (1.0f + erff(nrm * 0.70710678118f));
                int n = w * 64 + ct * 16 + (l & 15);
                out[(size_t)r * DOUT + n] = g + p[rt][ct][j];
            }
        }
    }
}

extern "C" void kernel_launch(void* const* d_in, const int* in_sizes, int n_in,
                              void* d_out, int out_size, void* d_ws, size_t ws_size,
                              hipStream_t stream) {
    const float* x      = (const float*)d_in[0];
    const int*   ei     = (const int*)d_in[1];
    const float* W_l    = (const float*)d_in[2];
    const float* b_l    = (const float*)d_in[3];
    const float* W_r    = (const float*)d_in[4];
    const float* gamma  = (const float*)d_in[5];
    const float* beta   = (const float*)d_in[6];
    const float* W_proj = (const float*)d_in[7];
    float* out = (float*)d_out;

    char* ws = (char*)d_ws;
    unsigned short* pkWl = (unsigned short*)(ws + WS_PKL);
    unsigned short* pkWr = (unsigned short*)(ws + WS_PKR);
    unsigned short* pkWp = (unsigned short*)(ws + WS_PKP);
    float* agg     = (float*)(ws + WS_AGG);
    int*   cntI    = (int*)(ws + WS_CNTI);
    int*   offsets = (int*)(ws + WS_OFFS);
    int*   cursor  = (int*)(ws + WS_CURS);
    int*   bs1     = (int*)(ws + WS_BS1);
    int*   bs2     = (int*)(ws + WS_BS2);
    int*   srcIdx  = (int*)(ws + WS_SRCI);

    hipMemsetAsync(cntI, 0, (size_t)NN * 4, stream);   // histogram must start at 0

    pack_w_kernel<<<16, 256, 0, stream>>>(W_l, pkWl);
    pack_w_kernel<<<16, 256, 0, stream>>>(W_r, pkWr);
    pack_w_kernel<<<16, 256, 0, stream>>>(W_proj, pkWp);

    count_kernel<<<(NE + 255) / 256, 256, 0, stream>>>(ei, cntI);
    scan_block_sums<<<NBLK_SCAN, 256, 0, stream>>>(cntI, bs1);
    scan_partials<<<1, 512, 0, stream>>>(bs1, bs2);
    scan_final<<<NBLK_SCAN, 256, 0, stream>>>(cntI, bs2, offsets, cursor);
    scatter_kernel<<<(NE + 255) / 256, 256, 0, stream>>>(ei, cursor, srcIdx);
    csr_aggregate<<<(NN + 3) / 4, 256, 0, stream>>>(x, srcIdx, offsets, agg);

    fused_mfma_kernel<<<(NN + 63) / 64, 256, 0, stream>>>(
        x, agg, pkWl, pkWr, pkWp, b_l, gamma, beta, out);
}